// Round 4
// baseline (76.372 us; speedup 1.0000x reference)
//
#include <hip/hip_runtime.h>

// modReLU: out = relu(|x|+b) * x/|x| for x != 0, else x (which is 0).
// Elementwise, memory-bound. 16B vectorized, nontemporal, 2x unrolled
// grid-stride with loads hoisted for deeper MLP.

typedef float fvec4 __attribute__((ext_vector_type(4)));

__device__ __forceinline__ fvec4 modrelu4(fvec4 re, fvec4 im, fvec4 b, fvec4& oim) {
    fvec4 ore;
    #pragma unroll
    for (int j = 0; j < 4; ++j) {
        float d   = re[j] * re[j] + im[j] * im[j];
        float irs = (d > 0.0f) ? __frsqrt_rn(d) : 0.0f;
        float r   = d * irs;                        // |x|
        float s   = fmaxf(r + b[j], 0.0f) * irs;    // relu(r+b)/r
        ore[j] = s * re[j];
        oim[j] = s * im[j];
    }
    return ore;
}

__global__ void modrelu_kernel(const fvec4* __restrict__ xre,
                               const fvec4* __restrict__ xim,
                               const fvec4* __restrict__ bias,   // 32 vecs (C=128)
                               fvec4* __restrict__ out_re,
                               fvec4* __restrict__ out_im,
                               int nvec) {
    const int T = gridDim.x * blockDim.x;
    int i = blockIdx.x * blockDim.x + threadIdx.x;

    for (; i + T < nvec; i += 2 * T) {
        // hoist all four input loads (two iterations' worth) before any compute
        fvec4 re0 = __builtin_nontemporal_load(&xre[i]);
        fvec4 im0 = __builtin_nontemporal_load(&xim[i]);
        fvec4 re1 = __builtin_nontemporal_load(&xre[i + T]);
        fvec4 im1 = __builtin_nontemporal_load(&xim[i + T]);
        fvec4 b0  = bias[i & 31];
        fvec4 b1  = bias[(i + T) & 31];

        fvec4 oim0, oim1;
        fvec4 ore0 = modrelu4(re0, im0, b0, oim0);
        fvec4 ore1 = modrelu4(re1, im1, b1, oim1);

        __builtin_nontemporal_store(ore0, &out_re[i]);
        __builtin_nontemporal_store(oim0, &out_im[i]);
        __builtin_nontemporal_store(ore1, &out_re[i + T]);
        __builtin_nontemporal_store(oim1, &out_im[i + T]);
    }
    if (i < nvec) {
        fvec4 re = __builtin_nontemporal_load(&xre[i]);
        fvec4 im = __builtin_nontemporal_load(&xim[i]);
        fvec4 b  = bias[i & 31];
        fvec4 oim;
        fvec4 ore = modrelu4(re, im, b, oim);
        __builtin_nontemporal_store(ore, &out_re[i]);
        __builtin_nontemporal_store(oim, &out_im[i]);
    }
}

extern "C" void kernel_launch(void* const* d_in, const int* in_sizes, int n_in,
                              void* d_out, int out_size, void* d_ws, size_t ws_size,
                              hipStream_t stream) {
    const float* x_re = (const float*)d_in[0];
    const float* x_im = (const float*)d_in[1];
    const float* bias = (const float*)d_in[2];
    float* out = (float*)d_out;

    const int total = in_sizes[0];        // N*C = 25,600,000
    const int nvec  = total / 4;          // 6,400,000 vecs

    float* out_re = out;                  // [N, C]
    float* out_im = out + total;          // [N, C]

    const int block = 256;
    int grid = (nvec + block - 1) / block;
    if (grid > 2048) grid = 2048;         // 256 CU x 8 blocks, 2x-unrolled grid-stride

    modrelu_kernel<<<grid, block, 0, stream>>>(
        (const fvec4*)x_re, (const fvec4*)x_im, (const fvec4*)bias,
        (fvec4*)out_re, (fvec4*)out_im, nvec);
}

// Round 5
// 71.278 us; speedup vs baseline: 1.0715x; 1.0715x over previous
//
#include <hip/hip_runtime.h>

// modReLU: out = relu(|x|+b) * x/|x| for x != 0, else x (which is 0).
// Elementwise, memory-bound. 16B vectorized, nontemporal, exact grid
// (one float4 per thread, no grid-stride loop).

typedef float fvec4 __attribute__((ext_vector_type(4)));

__global__ void __launch_bounds__(256) modrelu_kernel(
                               const fvec4* __restrict__ xre,
                               const fvec4* __restrict__ xim,
                               const fvec4* __restrict__ bias,   // 32 vecs (C=128)
                               fvec4* __restrict__ out_re,
                               fvec4* __restrict__ out_im,
                               int nvec) {
    int i = blockIdx.x * blockDim.x + threadIdx.x;
    if (i >= nvec) return;

    fvec4 re = __builtin_nontemporal_load(&xre[i]);
    fvec4 im = __builtin_nontemporal_load(&xim[i]);
    fvec4 b  = bias[i & 31];   // C/4 = 32 vecs per row; L1/L2-resident

    fvec4 ore, oim;
    #pragma unroll
    for (int j = 0; j < 4; ++j) {
        float d   = re[j] * re[j] + im[j] * im[j];
        float irs = (d > 0.0f) ? __frsqrt_rn(d) : 0.0f;
        float r   = d * irs;                        // |x|
        float s   = fmaxf(r + b[j], 0.0f) * irs;    // relu(r+b)/r
        ore[j] = s * re[j];
        oim[j] = s * im[j];
    }

    __builtin_nontemporal_store(ore, &out_re[i]);
    __builtin_nontemporal_store(oim, &out_im[i]);
}

extern "C" void kernel_launch(void* const* d_in, const int* in_sizes, int n_in,
                              void* d_out, int out_size, void* d_ws, size_t ws_size,
                              hipStream_t stream) {
    const float* x_re = (const float*)d_in[0];
    const float* x_im = (const float*)d_in[1];
    const float* bias = (const float*)d_in[2];
    float* out = (float*)d_out;

    const int total = in_sizes[0];        // N*C = 25,600,000
    const int nvec  = total / 4;          // 6,400,000 vecs

    float* out_re = out;                  // [N, C]
    float* out_im = out + total;          // [N, C]

    const int block = 256;
    const int grid = (nvec + block - 1) / block;   // exact grid: 25,000 blocks

    modrelu_kernel<<<grid, block, 0, stream>>>(
        (const fvec4*)x_re, (const fvec4*)x_im, (const fvec4*)bias,
        (fvec4*)out_re, (fvec4*)out_im, nvec);
}